// Round 10
// baseline (154.991 us; speedup 1.0000x reference)
//
#include <hip/hip_runtime.h>

// RepulsionXTB: per-pair repulsion energy, segment-summed per molecule.
//
// Inputs (setup_inputs order, harness converts ints to int32):
//   d_in[0] element_idxs  int32  [M*A]   (M=2048, A=64 -> 131072)
//   d_in[1] neighbor_idxs int32  [2*P]   (P=8388608)
//   d_in[2] distances     f32    [P]
//   d_in[3] y_ab          f32    [16]
//   d_in[4] sqrt_alpha_ab f32    [16]
//   d_in[5] k_rep_ab      f32    [16]   (1.5 everywhere except [0,0]=1.0)
// Output: energies f32 [M]
//
// R13 notes: cost model now complete. R10 ablation: atomic=23us, rest=26us.
// R12 null: LDS atomicAdd was already native ds_add_f32. Per-CU the kernel
// issues 8192 scattered wave64 ds-ops (2 pk b32 reads + 1 tbl b64 read +
// 1 ds_add per pair) ~= 80-100K cycles of a 124K-cycle kernel: the DS PIPE
// is the saturated resource (explains all R4-R9 scheduling nulls). Lever =
// ds-op count. This round deletes the tbl ds_read_b64: y_ab and
// sqrt_alpha_ab are rank-1 outer products, so per-element factors live in
// SGPRs (read from table diagonals) and the pair value is 12 v_cndmask +
// 2 mul on the 16%-busy VALU pipe. kr generality kept via 16-bit SGPR mask.
// Per pair: ds-ops 4->3, bank-passes ~6->~4.

#define AB_D 1.8897261258369282
#define L2E  1.4426950408889634f   // log2(e)

// ---------------- kernel 1: pack species to 2 bits/atom + zero output -------
__global__ __launch_bounds__(256) void pack_zero_kernel(
    const int* __restrict__ elem, int natoms, int nwords,
    unsigned* __restrict__ packed, float* __restrict__ out, int M)
{
    int g = blockIdx.x * blockDim.x + threadIdx.x;
    if (g < M) out[g] = 0.0f;
    if (packed != nullptr && g < nwords) {
        int base = g * 16;
        unsigned w = 0u;
        if (base + 16 <= natoms) {
            const int4* p = (const int4*)(elem + base);
            #pragma unroll
            for (int q = 0; q < 4; ++q) {
                int4 v = p[q];
                w |= ((unsigned)v.x & 3u) << (2 * (4 * q + 0));
                w |= ((unsigned)v.y & 3u) << (2 * (4 * q + 1));
                w |= ((unsigned)v.z & 3u) << (2 * (4 * q + 2));
                w |= ((unsigned)v.w & 3u) << (2 * (4 * q + 3));
            }
        } else {
            for (int j = 0; j < 16; ++j) {
                int a = base + j;
                unsigned s = (a < natoms) ? ((unsigned)elem[a] & 3u) : 0u;
                w |= s << (2 * j);
            }
        }
        packed[g] = w;
    }
}

// ---------------- kernel 2: main pair loop (tbl read -> SGPR factors) -------
// LDS layout: [acc: M f32][pk: nwords u32]
__global__ __launch_bounds__(1024, 8) void rep_main_kernel(
    const int* __restrict__ nbr, const float* __restrict__ dist,
    const unsigned* __restrict__ packed_g,
    const float* __restrict__ y_ab, const float* __restrict__ sa_ab,
    const float* __restrict__ kr_ab,
    long long P, int M, int nwords, int ashift, int A,
    float* __restrict__ partials, float* __restrict__ out,
    int mode /*0 = write partial row, 1 = global atomics*/)
{
    extern __shared__ char smem[];
    float*  acc = (float*)smem;
    unsigned* pk = (unsigned*)(smem + (size_t)M * 4);

    const int tid = threadIdx.x;
    const int nthr = blockDim.x;

    for (int m = tid; m < M; m += nthr) acc[m] = 0.0f;
    for (int w = tid; w < nwords; w += nthr) pk[w] = packed_g[w];

    // uniform per-element factors (compiler keeps these scalar):
    //   gy[i] = y_i        = sqrt(y_ab[i][i])
    //   fa[i] = sqrt(a_i*L2E)  so fa[s0]*fa[s1] = sqrt(a0*a1)*L2E
    const float gy0 = __builtin_amdgcn_sqrtf(y_ab[0]);
    const float gy1 = __builtin_amdgcn_sqrtf(y_ab[5]);
    const float gy2 = __builtin_amdgcn_sqrtf(y_ab[10]);
    const float gy3 = __builtin_amdgcn_sqrtf(y_ab[15]);
    const float fa0 = __builtin_amdgcn_sqrtf(sa_ab[0]  * L2E);
    const float fa1 = __builtin_amdgcn_sqrtf(sa_ab[5]  * L2E);
    const float fa2 = __builtin_amdgcn_sqrtf(sa_ab[10] * L2E);
    const float fa3 = __builtin_amdgcn_sqrtf(sa_ab[15] * L2E);
    unsigned krmask = 0u;                         // bit i: kr_ab[i] == 1.0
    #pragma unroll
    for (int i = 0; i < 16; ++i)
        krmask |= (kr_ab[i] == 1.0f ? 1u : 0u) << i;
    __syncthreads();

    const float ABf    = (float)AB_D;
    const float DMIN   = (float)(1e-7 * AB_D);
    const float RC     = (float)(5.2 * AB_D);
    const float RCINV  = (float)(1.0 / (5.2 * AB_D));
    const int* nb0 = nbr;
    const int* nb1 = nbr + P;

    // 4-way select from uniform constants: 3 v_cndmask
    auto sel4 = [](float c0, float c1, float c2, float c3, unsigned s) {
        float lo = (s & 1u) ? c1 : c0;
        float hi = (s & 1u) ? c3 : c2;
        return (s & 2u) ? hi : lo;
    };

    auto process = [&](int a0, int a1, float draw) {
        float d = fmaxf(draw * ABf, DMIN);
        if (d < RC) {
            unsigned ua0 = (unsigned)a0, ua1 = (unsigned)a1;
            unsigned w0 = pk[ua0 >> 4];
            unsigned w1 = pk[ua1 >> 4];
            unsigned s0 = (w0 >> ((ua0 & 15u) * 2u)) & 3u;
            unsigned s1 = (w1 >> ((ua1 & 15u) * 2u)) & 3u;

            float y   = sel4(gy0, gy1, gy2, gy3, s0) * sel4(gy0, gy1, gy2, gy3, s1);
            float sal = sel4(fa0, fa1, fa2, fa3, s0) * sel4(fa0, fa1, fa2, fa3, s1);
            unsigned idx = s0 * 4u + s1;

            float sq   = __builtin_amdgcn_sqrtf(d);
            float fac  = ((krmask >> idx) & 1u) ? 1.0f : sq;   // kr==1 ? d : d^1.5
            float drep = d * fac;
            float x    = d * RCINV;
            float om   = fmaf(-x, x, 1.0f);            // >= 0 inside cutoff
            float r    = __builtin_amdgcn_rcpf(om);    // om==0 -> +inf -> exp2(-inf)=0
            float e    = fmaf(-L2E, r, L2E);           // log2e*(1 - 1/om)
            float arg  = fmaf(-sal, drep, e);
            float ex   = __builtin_amdgcn_exp2f(arg);
            float rep  = y * __builtin_amdgcn_rcpf(d) * ex;

            unsigned mol = (ashift >= 0) ? (ua0 >> ashift) : (ua0 / (unsigned)A);
            unsafeAtomicAdd(&acc[mol], rep);           // native ds_add_f32
        }
    };

    long long P4 = P >> 2;
    long long gstride = (long long)gridDim.x * nthr;
    for (long long q = (long long)blockIdx.x * nthr + tid; q < P4; q += gstride) {
        int4   i0 = ((const int4*)nb0)[q];
        int4   i1 = ((const int4*)nb1)[q];
        float4 dv = ((const float4*)dist)[q];
        process(i0.x, i1.x, dv.x);
        process(i0.y, i1.y, dv.y);
        process(i0.z, i1.z, dv.z);
        process(i0.w, i1.w, dv.w);
    }
    // tail (P not divisible by 4) — handled by block 0 (empty for P=8.4M)
    long long tail0 = P4 << 2;
    if (blockIdx.x == 0) {
        for (long long p = tail0 + tid; p < P; p += nthr)
            process(nb0[p], nb1[p], dist[p]);
    }
    __syncthreads();

    if (mode == 0) {
        float* row = partials + (size_t)blockIdx.x * (size_t)M;
        for (int m = tid; m < M; m += nthr) row[m] = acc[m];
    } else {
        for (int m = tid; m < M; m += nthr) {
            float v = acc[m];
            if (v != 0.0f) unsafeAtomicAdd(&out[m], v);
        }
    }
}

// ---------------- kernel 3: column-sum the partial rows ---------------------
__global__ __launch_bounds__(256) void reduce_kernel(
    const float* __restrict__ partials, float* __restrict__ out,
    int M, int nblk, int rows_per)
{
    int m = blockIdx.x * blockDim.x + threadIdx.x;
    if (m >= M) return;
    int r0 = blockIdx.y * rows_per;
    int r1 = r0 + rows_per;
    if (r1 > nblk) r1 = nblk;
    if (r0 >= r1) return;
    float s0 = 0.f, s1 = 0.f, s2 = 0.f, s3 = 0.f;
    int r = r0;
    for (; r + 3 < r1; r += 4) {
        s0 += partials[(size_t)(r + 0) * M + m];
        s1 += partials[(size_t)(r + 1) * M + m];
        s2 += partials[(size_t)(r + 2) * M + m];
        s3 += partials[(size_t)(r + 3) * M + m];
    }
    for (; r < r1; ++r) s0 += partials[(size_t)r * M + m];
    unsafeAtomicAdd(&out[m], (s0 + s1) + (s2 + s3));
}

extern "C" void kernel_launch(void* const* d_in, const int* in_sizes, int n_in,
                              void* d_out, int out_size, void* d_ws, size_t ws_size,
                              hipStream_t stream)
{
    const int*   elem  = (const int*)d_in[0];
    const int*   nbr   = (const int*)d_in[1];
    const float* dist  = (const float*)d_in[2];
    const float* y_ab  = (const float*)d_in[3];
    const float* sa_ab = (const float*)d_in[4];
    const float* kr_ab = (const float*)d_in[5];
    float* out = (float*)d_out;

    const int natoms = in_sizes[0];
    const long long P = (long long)in_sizes[2];
    const int M = out_size;
    const int A = natoms / M;
    int ashift = -1;
    if (A > 0 && (A & (A - 1)) == 0) {
        int s = 0;
        while ((1 << s) < A) ++s;
        ashift = s;
    }
    const int nwords = (natoms + 15) / 16;

    // workspace layout: [packed: nwords u32 (256B aligned)][partials: nblk*M f32]
    size_t packed_bytes = ((size_t)nwords * 4 + 255) & ~(size_t)255;
    bool have_packed = (ws_size >= packed_bytes);
    unsigned* packed = have_packed ? (unsigned*)d_ws : nullptr;
    if (!have_packed) return;  // harness always provides workspace

    const int BLOCK = 1024;
    int nblk = 512;            // 2 blocks/CU on 256 CUs -> 32 waves/CU
    float* partials = nullptr;
    int mode = 1;              // global-atomic fallback
    {
        size_t avail = ws_size - packed_bytes;
        size_t rowb = (size_t)M * 4;
        long long maxrows = (long long)(avail / rowb);
        if (maxrows >= 64) {
            nblk = (int)(maxrows < 512 ? maxrows : 512);
            partials = (float*)((char*)d_ws + packed_bytes);
            mode = 0;
        }
    }

    // kernel 1: pack + zero out
    {
        int total = (nwords > M) ? nwords : M;
        int g = (total + 255) / 256;
        hipLaunchKernelGGL(pack_zero_kernel, dim3(g), dim3(256), 0, stream,
                           elem, natoms, nwords, packed, out, M);
    }

    // kernel 2: main
    {
        size_t smem = (size_t)M * 4 + (size_t)nwords * 4;
        hipLaunchKernelGGL(rep_main_kernel, dim3(nblk), dim3(BLOCK), smem, stream,
                           nbr, dist, packed, y_ab, sa_ab, kr_ab,
                           P, M, nwords, ashift, A, partials, out, mode);
    }

    // kernel 3: reduce partial rows
    if (mode == 0) {
        const int SPLIT = 32;
        int rows_per = (nblk + SPLIT - 1) / SPLIT;
        dim3 grid((M + 255) / 256, SPLIT);
        hipLaunchKernelGGL(reduce_kernel, grid, dim3(256), 0, stream,
                           partials, out, M, nblk, rows_per);
    }
}